// Round 7
// baseline (143.014 us; speedup 1.0000x reference)
//
#include <hip/hip_runtime.h>
#include <cstdint>

// ---------------------------------------------------------------------------
// Composer_81707457839189:
//   Vmin = min(V, axis=0);  Vcorr = max(V - Vmin + e, e)
//   phi  = (1+w)*Vcorr + b
//   G    = triu(gammas,1) + triu(gammas,1)^T
//   P[n,i,j] = phi_i^G * phi_j^(1-G)  (diag = phi_i);  modal = sum_j P
//   logits = log_softmax(-0.25*modal);  alphas = exp(logits)
// Output: d_out = [alphas (N*16) | logits (N*16)] fp32
//
// ws layout: column-min c at ws[c*16] (one 64B line per column so the 16
// atomicMin streams from 1024 blocks don't serialize on a single line).
//
// NOTE (R5 post-mortem): do NOT use __builtin_nontemporal_store for the
// output epilogue. Each wave store touches 64 lines at 16B/line (row stride
// 64B); L2 write-combining merges the 4 quarter-line writes — nt bypasses
// it and caused 2.6x HBM write amplification (166MB vs 64MB, k_main 25->94us).
//
// R6: k_main processes 2 rows/thread (interleaved) — halves s_g LDS reads
// per row and doubles independent trans chains (issue-bound kernel).
// ---------------------------------------------------------------------------

#define EC    2.71828182845904523536f
#define LOG2E 1.44269504088896340736f
#define LN2   0.69314718055994530942f

__device__ __forceinline__ unsigned int ordmap(float f) {
    unsigned int u = __float_as_uint(f);
    return u ^ ((unsigned int)((int)u >> 31) | 0x80000000u);
}
__device__ __forceinline__ float ordunmap(unsigned int u) {
    unsigned int bits = (u & 0x80000000u) ? (u ^ 0x80000000u) : ~u;
    return __uint_as_float(bits);
}

// ws[0..255] <- +inf (mapped). ws is re-poisoned to 0xAA before every timed
// launch, so this init must run on every kernel_launch call.
__global__ void k_init(unsigned int* __restrict__ ws) {
    ws[threadIdx.x] = 0xFFFFFFFFu;   // covers the 16 padded slots
}

// Per-column min of V (N x 16, row-major) via ordered-uint atomicMin.
// Flat float4 view: float4 element i, slot k holds column 4*(i%4)+k.
// Grid stride is a multiple of 4, so each thread owns one fixed column group.
__global__ __launch_bounds__(256) void k_colmin(const float4* __restrict__ V4,
                                                unsigned int* __restrict__ ws,
                                                int n4) {
    int tid = blockIdx.x * blockDim.x + threadIdx.x;
    int stride = gridDim.x * blockDim.x;  // multiple of 4
    float4 m = make_float4(__builtin_inff(), __builtin_inff(),
                           __builtin_inff(), __builtin_inff());
    for (int i = tid; i < n4; i += stride) {
        float4 v = V4[i];
        m.x = fminf(m.x, v.x);
        m.y = fminf(m.y, v.y);
        m.z = fminf(m.z, v.z);
        m.w = fminf(m.w, v.w);
    }
    // Fold lanes sharing lane%4 (xor over bits 2..5 of the lane id).
    #pragma unroll
    for (int off = 4; off <= 32; off <<= 1) {
        m.x = fminf(m.x, __shfl_xor(m.x, off));
        m.y = fminf(m.y, __shfl_xor(m.y, off));
        m.z = fminf(m.z, __shfl_xor(m.z, off));
        m.w = fminf(m.w, __shfl_xor(m.w, off));
    }
    __shared__ float lmin[4][16];
    int lane = threadIdx.x & 63;
    int wv   = threadIdx.x >> 6;
    if (lane < 4) {  // lane == column group
        lmin[wv][lane * 4 + 0] = m.x;
        lmin[wv][lane * 4 + 1] = m.y;
        lmin[wv][lane * 4 + 2] = m.z;
        lmin[wv][lane * 4 + 3] = m.w;
    }
    __syncthreads();
    if (threadIdx.x < 16) {
        float mm = fminf(fminf(lmin[0][threadIdx.x], lmin[1][threadIdx.x]),
                         fminf(lmin[2][threadIdx.x], lmin[3][threadIdx.x]));
        atomicMin(&ws[threadIdx.x * 16], ordmap(mm));   // one line per column
    }
}

// 2 rows per thread: r0 = blk*512 + t, r1 = r0 + 256.
__global__ __launch_bounds__(256) void k_main(const float* __restrict__ V,
                                              const float* __restrict__ w,
                                              const float* __restrict__ b,
                                              const float* __restrict__ gam,
                                              const unsigned int* __restrict__ wsmin,
                                              float* __restrict__ out, int N) {
    __shared__ float s_cw[16], s_cb[16], s_vmin[16];
    __shared__ float s_g[16][16];
    int t = threadIdx.x;
    if (t < 16) {
        s_cw[t]   = 1.0f + w[t];
        s_cb[t]   = b[t];
        s_vmin[t] = ordunmap(wsmin[t * 16]);
    }
    {   // symmetrize gammas: G[i][j] = gammas[min(i,j)][max(i,j)], diag unused
        int i = t >> 4, j = t & 15;
        s_g[i][j] = (i < j) ? gam[i * 16 + j] : ((i > j) ? gam[j * 16 + i] : 0.0f);
    }
    __syncthreads();

    int r0 = blockIdx.x * (blockDim.x * 2) + t;
    int r1 = r0 + 256;
    if (r0 >= N) return;
    bool has1 = (r1 < N);
    int r1c = has1 ? r1 : r0;   // clamp: in-bounds load, store predicated

    const float4* V0 = (const float4*)(V + (size_t)r0  * 16);
    const float4* V1 = (const float4*)(V + (size_t)r1c * 16);
    float4 a0 = V0[0], a1 = V0[1], a2 = V0[2], a3 = V0[3];
    float4 b0 = V1[0], b1 = V1[1], b2 = V1[2], b3 = V1[3];
    float vf0[16] = {a0.x, a0.y, a0.z, a0.w, a1.x, a1.y, a1.z, a1.w,
                     a2.x, a2.y, a2.z, a2.w, a3.x, a3.y, a3.z, a3.w};
    float vf1[16] = {b0.x, b0.y, b0.z, b0.w, b1.x, b1.y, b1.z, b1.w,
                     b2.x, b2.y, b2.z, b2.w, b3.x, b3.y, b3.z, b3.w};

    float L0[16], L1[16], m0[16], m1[16];
    #pragma unroll
    for (int i = 0; i < 16; ++i) {
        float vm = s_vmin[i], cw = s_cw[i], cb = s_cb[i];
        float p0 = __builtin_fmaf(cw, fmaxf(vf0[i] - vm + EC, EC), cb);
        float p1 = __builtin_fmaf(cw, fmaxf(vf1[i] - vm + EC, EC), cb);
        L0[i] = __builtin_amdgcn_logf(p0);   // v_log_f32 (log2)
        L1[i] = __builtin_amdgcn_logf(p1);
        m0[i] = p0;                           // diagonal term
        m1[i] = p1;
    }

    // P[i,j] = exp2(L[j] + g*d), P[j,i] = exp2(L[i] - g*d), d = L[i]-L[j]
    #pragma unroll
    for (int i = 0; i < 16; ++i) {
        #pragma unroll
        for (int j = i + 1; j < 16; ++j) {
            float g  = s_g[i][j];             // one broadcast feeds 4 exps
            float d0 = L0[i] - L0[j];
            float d1 = L1[i] - L1[j];
            m0[i] += __builtin_amdgcn_exp2f(__builtin_fmaf(g,  d0, L0[j]));
            m0[j] += __builtin_amdgcn_exp2f(__builtin_fmaf(-g, d0, L0[i]));
            m1[i] += __builtin_amdgcn_exp2f(__builtin_fmaf(g,  d1, L1[j]));
            m1[j] += __builtin_amdgcn_exp2f(__builtin_fmaf(-g, d1, L1[i]));
        }
    }

    // log-softmax of x = -0.25 * modal, both rows
    float x0[16], x1[16];
    float mx0 = -__builtin_inff(), mx1 = -__builtin_inff();
    #pragma unroll
    for (int i = 0; i < 16; ++i) {
        x0[i] = -0.25f * m0[i];  mx0 = fmaxf(mx0, x0[i]);
        x1[i] = -0.25f * m1[i];  mx1 = fmaxf(mx1, x1[i]);
    }
    float e0[16], e1[16], s0 = 0.0f, s1 = 0.0f;
    #pragma unroll
    for (int i = 0; i < 16; ++i) {
        e0[i] = __builtin_amdgcn_exp2f((x0[i] - mx0) * LOG2E);  s0 += e0[i];
        e1[i] = __builtin_amdgcn_exp2f((x1[i] - mx1) * LOG2E);  s1 += e1[i];
    }
    float inv0 = 1.0f / s0, inv1 = 1.0f / s1;
    float off0 = mx0 + __builtin_amdgcn_logf(s0) * LN2;  // mx + ln(s)
    float off1 = mx1 + __builtin_amdgcn_logf(s1) * LN2;

    {
        float4* oa = (float4*)(out + (size_t)r0 * 16);
        float4* ol = (float4*)(out + (size_t)N * 16 + (size_t)r0 * 16);
        #pragma unroll
        for (int q = 0; q < 4; ++q) {
            oa[q] = make_float4(e0[q*4+0]*inv0, e0[q*4+1]*inv0,
                                e0[q*4+2]*inv0, e0[q*4+3]*inv0);
            ol[q] = make_float4(x0[q*4+0]-off0, x0[q*4+1]-off0,
                                x0[q*4+2]-off0, x0[q*4+3]-off0);
        }
    }
    if (has1) {
        float4* oa = (float4*)(out + (size_t)r1 * 16);
        float4* ol = (float4*)(out + (size_t)N * 16 + (size_t)r1 * 16);
        #pragma unroll
        for (int q = 0; q < 4; ++q) {
            oa[q] = make_float4(e1[q*4+0]*inv1, e1[q*4+1]*inv1,
                                e1[q*4+2]*inv1, e1[q*4+3]*inv1);
            ol[q] = make_float4(x1[q*4+0]-off1, x1[q*4+1]-off1,
                                x1[q*4+2]-off1, x1[q*4+3]-off1);
        }
    }
}

extern "C" void kernel_launch(void* const* d_in, const int* in_sizes, int n_in,
                              void* d_out, int out_size, void* d_ws, size_t ws_size,
                              hipStream_t stream) {
    (void)n_in; (void)out_size; (void)ws_size;
    const float* V   = (const float*)d_in[0];
    const float* w   = (const float*)d_in[1];
    const float* b   = (const float*)d_in[2];
    const float* gam = (const float*)d_in[3];
    float* out = (float*)d_out;
    unsigned int* wsmin = (unsigned int*)d_ws;

    const int N  = in_sizes[0] / 16;
    const int n4 = N * 4;  // float4 count

    hipLaunchKernelGGL(k_init, dim3(1), dim3(256), 0, stream, wsmin);
    hipLaunchKernelGGL(k_colmin, dim3(1024), dim3(256), 0, stream,
                       (const float4*)V, wsmin, n4);
    hipLaunchKernelGGL(k_main, dim3((N + 511) / 512), dim3(256), 0, stream,
                       V, w, b, gam, wsmin, out, N);
}

// Round 8
// 137.983 us; speedup vs baseline: 1.0365x; 1.0365x over previous
//
#include <hip/hip_runtime.h>
#include <cstdint>

// ---------------------------------------------------------------------------
// Composer_81707457839189:
//   Vmin = min(V, axis=0);  Vcorr = max(V - Vmin + e, e)
//   phi  = (1+w)*Vcorr + b
//   G    = triu(gammas,1) + triu(gammas,1)^T
//   P[n,i,j] = phi_i^G * phi_j^(1-G)  (diag = phi_i);  modal = sum_j P
//   logits = log_softmax(-0.25*modal);  alphas = exp(logits)
// Output: d_out = [alphas (N*16) | logits (N*16)] fp32
//
// ws layout: column-min c at ws[c*16] (one 64B line per column).
//
// R5 post-mortem: NO nontemporal stores (2.6x HBM write amplification —
// L2 write-combining is essential for 16B-quarter-line output stores).
// R7 post-mortem: k_main is LATENCY-bound (VALUBusy*dur ~= 14us constant,
// dur 38-43us): lockstep load->compute->store phases + 120 LDS reads/row.
// R8: (a) zero LDS — g/w/b/vmin are wave-uniform with compile-time offsets
// (fully unrolled), so they become s_load from K$; for i<j, G[i][j] is just
// gammas[i*16+j] (no symmetrization needed on the upper triangle);
// (b) grid-stride with explicit next-row prefetch to overlap HBM latency
// with the ~2000-cycle compute block. 1 row/thread/iter keeps VGPR moderate.
// ---------------------------------------------------------------------------

#define EC    2.71828182845904523536f
#define LOG2E 1.44269504088896340736f
#define LN2   0.69314718055994530942f

__device__ __forceinline__ unsigned int ordmap(float f) {
    unsigned int u = __float_as_uint(f);
    return u ^ ((unsigned int)((int)u >> 31) | 0x80000000u);
}
__device__ __forceinline__ float ordunmap(unsigned int u) {
    unsigned int bits = (u & 0x80000000u) ? (u ^ 0x80000000u) : ~u;
    return __uint_as_float(bits);
}

// ws[0..255] <- +inf (mapped). ws is re-poisoned to 0xAA before every timed
// launch, so this init must run on every kernel_launch call.
__global__ void k_init(unsigned int* __restrict__ ws) {
    ws[threadIdx.x] = 0xFFFFFFFFu;   // covers the 16 padded slots
}

// Per-column min of V (N x 16, row-major) via ordered-uint atomicMin.
__global__ __launch_bounds__(256) void k_colmin(const float4* __restrict__ V4,
                                                unsigned int* __restrict__ ws,
                                                int n4) {
    int tid = blockIdx.x * blockDim.x + threadIdx.x;
    int stride = gridDim.x * blockDim.x;  // multiple of 4
    float4 m = make_float4(__builtin_inff(), __builtin_inff(),
                           __builtin_inff(), __builtin_inff());
    for (int i = tid; i < n4; i += stride) {
        float4 v = V4[i];
        m.x = fminf(m.x, v.x);
        m.y = fminf(m.y, v.y);
        m.z = fminf(m.z, v.z);
        m.w = fminf(m.w, v.w);
    }
    #pragma unroll
    for (int off = 4; off <= 32; off <<= 1) {
        m.x = fminf(m.x, __shfl_xor(m.x, off));
        m.y = fminf(m.y, __shfl_xor(m.y, off));
        m.z = fminf(m.z, __shfl_xor(m.z, off));
        m.w = fminf(m.w, __shfl_xor(m.w, off));
    }
    __shared__ float lmin[4][16];
    int lane = threadIdx.x & 63;
    int wv   = threadIdx.x >> 6;
    if (lane < 4) {
        lmin[wv][lane * 4 + 0] = m.x;
        lmin[wv][lane * 4 + 1] = m.y;
        lmin[wv][lane * 4 + 2] = m.z;
        lmin[wv][lane * 4 + 3] = m.w;
    }
    __syncthreads();
    if (threadIdx.x < 16) {
        float mm = fminf(fminf(lmin[0][threadIdx.x], lmin[1][threadIdx.x]),
                         fminf(lmin[2][threadIdx.x], lmin[3][threadIdx.x]));
        atomicMin(&ws[threadIdx.x * 16], ordmap(mm));   // one line per column
    }
}

// Grid-stride, 1 row/thread/iteration, next-row prefetch. Zero LDS: all
// per-mode constants are wave-uniform scalar loads (compile-time offsets).
__global__ __launch_bounds__(256) void k_main(const float* __restrict__ V,
                                              const float* __restrict__ w,
                                              const float* __restrict__ b,
                                              const float* __restrict__ gam,
                                              const unsigned int* __restrict__ wsmin,
                                              float* __restrict__ out, int N) {
    const int stride = gridDim.x * blockDim.x;
    int r = blockIdx.x * blockDim.x + threadIdx.x;
    if (r >= N) return;

    float4 c0, c1, c2, c3;
    {
        const float4* Vr = (const float4*)(V + (size_t)r * 16);
        c0 = Vr[0]; c1 = Vr[1]; c2 = Vr[2]; c3 = Vr[3];
    }

    for (;;) {
        int  rn   = r + stride;
        bool more = (rn < N);
        float4 n0, n1, n2, n3;
        if (more) {   // issue next-row loads BEFORE the compute block
            const float4* Vn = (const float4*)(V + (size_t)rn * 16);
            n0 = Vn[0]; n1 = Vn[1]; n2 = Vn[2]; n3 = Vn[3];
        }

        float vf[16] = {c0.x, c0.y, c0.z, c0.w, c1.x, c1.y, c1.z, c1.w,
                        c2.x, c2.y, c2.z, c2.w, c3.x, c3.y, c3.z, c3.w};

        float L[16], modal[16];
        #pragma unroll
        for (int i = 0; i < 16; ++i) {
            float vm = ordunmap(wsmin[i * 16]);            // s_load (uniform)
            float vc = fmaxf(vf[i] - vm + EC, EC);
            float p  = __builtin_fmaf(1.0f + w[i], vc, b[i]);  // s_load
            L[i]     = __builtin_amdgcn_logf(p);           // v_log_f32 (log2)
            modal[i] = p;                                   // diagonal term
        }

        // P[i,j] = exp2(L[j] + g*d), P[j,i] = exp2(L[i] - g*d), d=L[i]-L[j]
        // i<j  ==>  G[i][j] = gammas[i*16+j]  (upper triangle, no symmetrize)
        #pragma unroll
        for (int i = 0; i < 16; ++i) {
            #pragma unroll
            for (int j = i + 1; j < 16; ++j) {
                float g = gam[i * 16 + j];                 // s_load, K$-hot
                float d = L[i] - L[j];
                modal[i] += __builtin_amdgcn_exp2f(__builtin_fmaf(g,  d, L[j]));
                modal[j] += __builtin_amdgcn_exp2f(__builtin_fmaf(-g, d, L[i]));
            }
        }

        // log-softmax of x = -0.25 * modal
        float x[16];
        float mx = -__builtin_inff();
        #pragma unroll
        for (int i = 0; i < 16; ++i) {
            x[i] = -0.25f * modal[i];
            mx   = fmaxf(mx, x[i]);
        }
        float e[16], s = 0.0f;
        #pragma unroll
        for (int i = 0; i < 16; ++i) {
            e[i] = __builtin_amdgcn_exp2f((x[i] - mx) * LOG2E);
            s += e[i];
        }
        float inv = 1.0f / s;
        float off = mx + __builtin_amdgcn_logf(s) * LN2;   // mx + ln(s)

        float4* oa = (float4*)(out + (size_t)r * 16);
        float4* ol = (float4*)(out + (size_t)N * 16 + (size_t)r * 16);
        #pragma unroll
        for (int q = 0; q < 4; ++q) {
            oa[q] = make_float4(e[q*4+0]*inv, e[q*4+1]*inv,
                                e[q*4+2]*inv, e[q*4+3]*inv);
            ol[q] = make_float4(x[q*4+0]-off, x[q*4+1]-off,
                                x[q*4+2]-off, x[q*4+3]-off);
        }

        if (!more) break;
        c0 = n0; c1 = n1; c2 = n2; c3 = n3;
        r = rn;
    }
}

extern "C" void kernel_launch(void* const* d_in, const int* in_sizes, int n_in,
                              void* d_out, int out_size, void* d_ws, size_t ws_size,
                              hipStream_t stream) {
    (void)n_in; (void)out_size; (void)ws_size;
    const float* V   = (const float*)d_in[0];
    const float* w   = (const float*)d_in[1];
    const float* b   = (const float*)d_in[2];
    const float* gam = (const float*)d_in[3];
    float* out = (float*)d_out;
    unsigned int* wsmin = (unsigned int*)d_ws;

    const int N  = in_sizes[0] / 16;
    const int n4 = N * 4;  // float4 count

    hipLaunchKernelGGL(k_init, dim3(1), dim3(256), 0, stream, wsmin);
    hipLaunchKernelGGL(k_colmin, dim3(1024), dim3(256), 0, stream,
                       (const float4*)V, wsmin, n4);
    // 2 rows per thread via grid-stride (977 blocks); all waves co-resident,
    // prefetch hides the second row's load under the first row's compute.
    hipLaunchKernelGGL(k_main, dim3((N + 511) / 512), dim3(256), 0, stream,
                       V, w, b, gam, wsmin, out, N);
}